// Round 2
// baseline (918.979 us; speedup 1.0000x reference)
//
#include <hip/hip_runtime.h>
#include <math.h>

#define H 4096
#define E 64
#define T_TOTAL 32768
#define TB 64        // tokens per block
#define HK 128       // K-chunk in floats
#define NT 512       // threads per block (8 waves)
#define TPT 4        // tokens per thread

// d_out layout (floats):
//   logits : [0, 2097152)            = [4,8192,64]
//   weights: [2097152, 2162688)      = [32768,2]
//   indices: [2162688, 2228224)      = [32768,2] (written as float values)
#define OFF_W 2097152
#define OFF_I 2162688

__global__ __launch_bounds__(NT, 4)   // >=4 waves/SIMD -> VGPR cap 128
void moe_router_kernel(const float* __restrict__ x,
                       const float* __restrict__ W,
                       float* __restrict__ out)
{
    // Swizzled W chunk: row e, real column c4 (float4 units) stored at
    // column c4 ^ ((e>>1)&7). 32 KB -> 2 blocks/CU (16 waves/CU).
    __shared__ float ws[E * HK];

    const int tid = threadIdx.x;
    const int tx  = tid & 31;      // expert pair: experts 2tx, 2tx+1
    const int ty  = tid >> 5;      // token group: tokens ty*4 .. ty*4+3
    const int tok0 = blockIdx.x * TB;
    const int e0  = tx * 2;
    const int swz = tx & 7;

    // Per-thread token row base pointers (advance by HK each chunk).
    const float* p0 = x + (size_t)(tok0 + ty * TPT + 0) * H;
    const float* p1 = p0 + H;
    const float* p2 = p1 + H;
    const float* p3 = p2 + H;

    float acc[TPT][2];
#pragma unroll
    for (int i = 0; i < TPT; ++i) { acc[i][0] = 0.f; acc[i][1] = 0.f; }

    for (int kc = 0; kc < H / HK; ++kc) {
        // ---- stage W chunk into LDS (64 rows x 32 float4), swizzled ----
        __syncthreads();   // protect ws from previous iteration's readers
#pragma unroll
        for (int k = 0; k < 4; ++k) {
            int g  = tid + k * NT;           // 0..2047
            int e  = g >> 5;                 // 0..63
            int c4 = g & 31;                 // 0..31
            float4 v = *(const float4*)(W + (size_t)e * H + kc * HK + (c4 << 2));
            int c4s = c4 ^ ((e >> 1) & 7);
            *(float4*)(ws + e * HK + (c4s << 2)) = v;
        }
        __syncthreads();

        // ---- compute: 32 float4 K-steps, 2-buffer rotation, dist-2 PF ----
        float4 xa0 = *(const float4*)(p0 + 0), xa1 = *(const float4*)(p1 + 0),
               xa2 = *(const float4*)(p2 + 0), xa3 = *(const float4*)(p3 + 0);
        float4 xb0 = *(const float4*)(p0 + 4), xb1 = *(const float4*)(p1 + 4),
               xb2 = *(const float4*)(p2 + 4), xb3 = *(const float4*)(p3 + 4);

#pragma unroll
        for (int h4 = 0; h4 < 32; h4 += 2) {
            {
                const int col = ((h4 ^ swz) << 2);
                const float4 wv0 = *(const float4*)(ws + e0 * HK + col);
                const float4 wv1 = *(const float4*)(ws + (e0 + 1) * HK + col);
                acc[0][0] = fmaf(xa0.x, wv0.x, acc[0][0]); acc[0][0] = fmaf(xa0.y, wv0.y, acc[0][0]);
                acc[0][0] = fmaf(xa0.z, wv0.z, acc[0][0]); acc[0][0] = fmaf(xa0.w, wv0.w, acc[0][0]);
                acc[0][1] = fmaf(xa0.x, wv1.x, acc[0][1]); acc[0][1] = fmaf(xa0.y, wv1.y, acc[0][1]);
                acc[0][1] = fmaf(xa0.z, wv1.z, acc[0][1]); acc[0][1] = fmaf(xa0.w, wv1.w, acc[0][1]);
                acc[1][0] = fmaf(xa1.x, wv0.x, acc[1][0]); acc[1][0] = fmaf(xa1.y, wv0.y, acc[1][0]);
                acc[1][0] = fmaf(xa1.z, wv0.z, acc[1][0]); acc[1][0] = fmaf(xa1.w, wv0.w, acc[1][0]);
                acc[1][1] = fmaf(xa1.x, wv1.x, acc[1][1]); acc[1][1] = fmaf(xa1.y, wv1.y, acc[1][1]);
                acc[1][1] = fmaf(xa1.z, wv1.z, acc[1][1]); acc[1][1] = fmaf(xa1.w, wv1.w, acc[1][1]);
                acc[2][0] = fmaf(xa2.x, wv0.x, acc[2][0]); acc[2][0] = fmaf(xa2.y, wv0.y, acc[2][0]);
                acc[2][0] = fmaf(xa2.z, wv0.z, acc[2][0]); acc[2][0] = fmaf(xa2.w, wv0.w, acc[2][0]);
                acc[2][1] = fmaf(xa2.x, wv1.x, acc[2][1]); acc[2][1] = fmaf(xa2.y, wv1.y, acc[2][1]);
                acc[2][1] = fmaf(xa2.z, wv1.z, acc[2][1]); acc[2][1] = fmaf(xa2.w, wv1.w, acc[2][1]);
                acc[3][0] = fmaf(xa3.x, wv0.x, acc[3][0]); acc[3][0] = fmaf(xa3.y, wv0.y, acc[3][0]);
                acc[3][0] = fmaf(xa3.z, wv0.z, acc[3][0]); acc[3][0] = fmaf(xa3.w, wv0.w, acc[3][0]);
                acc[3][1] = fmaf(xa3.x, wv1.x, acc[3][1]); acc[3][1] = fmaf(xa3.y, wv1.y, acc[3][1]);
                acc[3][1] = fmaf(xa3.z, wv1.z, acc[3][1]); acc[3][1] = fmaf(xa3.w, wv1.w, acc[3][1]);
            }
            if (h4 + 2 < 32) {   // compile-time after unroll
                const int o = (h4 + 2) << 2;
                xa0 = *(const float4*)(p0 + o); xa1 = *(const float4*)(p1 + o);
                xa2 = *(const float4*)(p2 + o); xa3 = *(const float4*)(p3 + o);
            }
            {
                const int col = (((h4 + 1) ^ swz) << 2);
                const float4 wv0 = *(const float4*)(ws + e0 * HK + col);
                const float4 wv1 = *(const float4*)(ws + (e0 + 1) * HK + col);
                acc[0][0] = fmaf(xb0.x, wv0.x, acc[0][0]); acc[0][0] = fmaf(xb0.y, wv0.y, acc[0][0]);
                acc[0][0] = fmaf(xb0.z, wv0.z, acc[0][0]); acc[0][0] = fmaf(xb0.w, wv0.w, acc[0][0]);
                acc[0][1] = fmaf(xb0.x, wv1.x, acc[0][1]); acc[0][1] = fmaf(xb0.y, wv1.y, acc[0][1]);
                acc[0][1] = fmaf(xb0.z, wv1.z, acc[0][1]); acc[0][1] = fmaf(xb0.w, wv1.w, acc[0][1]);
                acc[1][0] = fmaf(xb1.x, wv0.x, acc[1][0]); acc[1][0] = fmaf(xb1.y, wv0.y, acc[1][0]);
                acc[1][0] = fmaf(xb1.z, wv0.z, acc[1][0]); acc[1][0] = fmaf(xb1.w, wv0.w, acc[1][0]);
                acc[1][1] = fmaf(xb1.x, wv1.x, acc[1][1]); acc[1][1] = fmaf(xb1.y, wv1.y, acc[1][1]);
                acc[1][1] = fmaf(xb1.z, wv1.z, acc[1][1]); acc[1][1] = fmaf(xb1.w, wv1.w, acc[1][1]);
                acc[2][0] = fmaf(xb2.x, wv0.x, acc[2][0]); acc[2][0] = fmaf(xb2.y, wv0.y, acc[2][0]);
                acc[2][0] = fmaf(xb2.z, wv0.z, acc[2][0]); acc[2][0] = fmaf(xb2.w, wv0.w, acc[2][0]);
                acc[2][1] = fmaf(xb2.x, wv1.x, acc[2][1]); acc[2][1] = fmaf(xb2.y, wv1.y, acc[2][1]);
                acc[2][1] = fmaf(xb2.z, wv1.z, acc[2][1]); acc[2][1] = fmaf(xb2.w, wv1.w, acc[2][1]);
                acc[3][0] = fmaf(xb3.x, wv0.x, acc[3][0]); acc[3][0] = fmaf(xb3.y, wv0.y, acc[3][0]);
                acc[3][0] = fmaf(xb3.z, wv0.z, acc[3][0]); acc[3][0] = fmaf(xb3.w, wv0.w, acc[3][0]);
                acc[3][1] = fmaf(xb3.x, wv1.x, acc[3][1]); acc[3][1] = fmaf(xb3.y, wv1.y, acc[3][1]);
                acc[3][1] = fmaf(xb3.z, wv1.z, acc[3][1]); acc[3][1] = fmaf(xb3.w, wv1.w, acc[3][1]);
            }
            if (h4 + 3 < 32) {
                const int o = (h4 + 3) << 2;
                xb0 = *(const float4*)(p0 + o); xb1 = *(const float4*)(p1 + o);
                xb2 = *(const float4*)(p2 + o); xb3 = *(const float4*)(p3 + o);
            }
        }

        p0 += HK; p1 += HK; p2 += HK; p3 += HK;
    }

    // ---- epilogue: logits to global + LDS tile for top-2 ----
    __syncthreads();                       // done reading ws as W
    float* lt = ws;                        // reuse as [64][65] logits tile
#pragma unroll
    for (int i = 0; i < TPT; ++i) {
        const int t = ty * TPT + i;
        lt[t * 65 + e0]     = acc[i][0];
        lt[t * 65 + e0 + 1] = acc[i][1];
        float2 o; o.x = acc[i][0]; o.y = acc[i][1];
        *(float2*)(out + (size_t)(tok0 + t) * E + e0) = o;
    }
    __syncthreads();

    if (tid < TB) {
        const float* row = lt + tid * 65;
        float v1 = -INFINITY, v2 = -INFINITY;
        int i1 = 0, i2 = 0;
        for (int e = 0; e < E; ++e) {
            float v = row[e];
            if (v > v1)      { v2 = v1; i2 = i1; v1 = v; i1 = e; }
            else if (v > v2) { v2 = v;  i2 = e; }
        }
        // softmax->top2->renorm == sigmoid of logit gap (Z cancels)
        float ee = expf(v2 - v1);          // <= 1
        float w1 = 1.0f / (1.0f + ee);
        float w2 = ee * w1;

        const size_t tok = (size_t)tok0 + tid;
        out[OFF_W + tok * 2]     = w1;
        out[OFF_W + tok * 2 + 1] = w2;
        out[OFF_I + tok * 2]     = (float)i1;
        out[OFF_I + tok * 2 + 1] = (float)i2;
    }
}

extern "C" void kernel_launch(void* const* d_in, const int* in_sizes, int n_in,
                              void* d_out, int out_size, void* d_ws, size_t ws_size,
                              hipStream_t stream) {
    const float* x = (const float*)d_in[0];
    const float* W = (const float*)d_in[1];
    float* out = (float*)d_out;

    dim3 grid(T_TOTAL / TB);   // 512 blocks
    dim3 block(NT);
    moe_router_kernel<<<grid, block, 0, stream>>>(x, W, out);
}